// Round 3
// baseline (355.143 us; speedup 1.0000x reference)
//
#include <hip/hip_runtime.h>

#define BDIM 256
#define SH 16

typedef float v2f __attribute__((ext_vector_type(2)));

struct LevelDesc {
    const float* lp; const float* rp; const float* dp;
    int H, W, nCW, nRS, nPerSide, waveBase;
};
struct AllParams { LevelDesc lv[4]; int totalWaves; };

// lane i <- lane i+1 (single VALU op: v_mov_b32 dpp wave_shl1).
// Lane 63 gets 0 (bound_ctrl) -- provably never consumed by ownership masks.
__device__ __forceinline__ float dpp_shl1(float x) {
    int r = __builtin_amdgcn_update_dpp(0, __float_as_int(x), 0x130, 0xF, 0xF, true);
    return __int_as_float(r);
}

// force a wave-uniform pointer into SGPRs -> saddr-form loads
__device__ __forceinline__ const float* uptr(const float* p) {
    unsigned long long u = (unsigned long long)p;
    unsigned lo = __builtin_amdgcn_readfirstlane((unsigned)u);
    unsigned hi = __builtin_amdgcn_readfirstlane((unsigned)(u >> 32));
    return (const float*)(((unsigned long long)hi << 32) | (unsigned long long)lo);
}

__device__ __forceinline__ v2f mkv(float a, float b) { v2f r; r.x = a; r.y = b; return r; }

// ---------------- kernels ----------------

// fused L+R align_corners bilinear resize (+ optional acc zeroing, saves a launch)
__global__ void resize2_kernel(const float* __restrict__ sL, const float* __restrict__ sR,
                               float* __restrict__ dL, float* __restrict__ dR,
                               int BC, int Hs, int Ws, int Hd, int Wd,
                               double* acc, int doZero) {
    if (doZero && blockIdx.x == 0 && threadIdx.x < 32) acc[threadIdx.x] = 0.0;
    long long half = (long long)BC * Hd * Wd;
    long long idx = (long long)blockIdx.x * blockDim.x + threadIdx.x;
    if (idx >= 2 * half) return;
    const float* src = (idx < half) ? sL : sR;
    float* dst = (idx < half) ? dL : dR;
    long long id = (idx < half) ? idx : idx - half;
    int i = (int)(id % Wd);
    long long t = id / Wd;
    int j = (int)(t % Hd);
    int bc = (int)(t / Hd);
    float stepy = (float)(Hs - 1) / (float)(Hd - 1);
    float stepx = (float)(Ws - 1) / (float)(Wd - 1);
    float y = j * stepy;
    float x = i * stepx;
    int y0 = (int)floorf(y);
    int y1 = min(y0 + 1, Hs - 1);
    int x0 = (int)floorf(x);
    int x1 = min(x0 + 1, Ws - 1);
    float wy = y - (float)y0;
    float wx = x - (float)x0;
    const float* s = src + (long long)bc * Hs * Ws;
    float t0 = s[(long long)y0 * Ws + x0] * (1.0f - wy) + s[(long long)y1 * Ws + x0] * wy;
    float t1 = s[(long long)y0 * Ws + x1] * (1.0f - wy) + s[(long long)y1 * Ws + x1] * wy;
    dst[id] = t0 * (1.0f - wx) + t1 * wx;
}

// packed (both px of a lane-pair) SSIM term -- bitwise-identical op order to scalar
__device__ __forceinline__ v2f ssim_term2(v2f Sx, v2f Sy, v2f Sxx, v2f Syy, v2f Sxy) {
    const float C1v = 0.0001f;
    const float C2v = 0.0009f;
    const float i9 = 1.0f / 9.0f;
    v2f mux = Sx * i9, muy = Sy * i9;
    v2f sigx = Sxx * i9 - mux * mux;
    v2f sigy = Syy * i9 - muy * muy;
    v2f cov  = Sxy * i9 - mux * muy;
    v2f num = ((2.0f * mux) * muy + C1v) * (2.0f * cov + C2v);
    v2f den = (mux * mux + muy * muy + C1v) * (sigx + sigy + C2v);
    v2f r;
    r.x = __builtin_amdgcn_rcpf(den.x);
    r.y = __builtin_amdgcn_rcpf(den.y);
    v2f v = (1.0f - num * r) * 0.5f;
    v2f o;
    o.x = fminf(fmaxf(v.x, 0.0f), 1.0f);
    o.y = fminf(fmaxf(v.y, 0.0f), 1.0f);
    return o;
}

// Per-row load stage (software pipeline buffer), pair-packed layout.
struct RowVals {
    float d0, d1;
    v2f xv[3];
    v2f wI, wJ;        // {w00,w10}, {w01,w11}
    v2f dI, dJ;        // {dot[a0],dot[b0]}, {dot[a1],dot[b1]}
    v2f sI[3], sJ[3];  // sampled-image gathers per channel
};

__global__ void __launch_bounds__(BDIM)
mega_kernel(AllParams P, double* __restrict__ acc) {
    const int lane = threadIdx.x & 63;
    const int wid  = threadIdx.x >> 6;
    const int wId  = blockIdx.x * (BDIM / 64) + wid;
    const int w = min(wId, P.totalWaves - 1);

    int level = 0;
    if (w >= P.lv[1].waveBase) level = 1;
    if (w >= P.lv[2].waveBase) level = 2;
    if (w >= P.lv[3].waveBase) level = 3;
    LevelDesc L;
    if (level == 0) L = P.lv[0];
    else if (level == 1) L = P.lv[1];
    else if (level == 2) L = P.lv[2];
    else L = P.lv[3];

    int rel = w - L.waveBase;
    const int side = (rel >= L.nPerSide) ? 1 : 0;
    rel -= side * L.nPerSide;
    const int cw = rel % L.nCW; rel /= L.nCW;
    const int rs = rel % L.nRS;
    const int b  = rel / L.nRS;

    const int H = L.H, W = L.W;
    const long long HW = (long long)H * W;
    const unsigned HWu = (unsigned)HW;
    const float Wm1f = (float)(W - 1);
    const float sgn = side ? 1.0f : -1.0f;

    const float* xim = uptr((side ? L.rp : L.lp) + (long long)b * 3 * HW);
    const float* sim = uptr((side ? L.lp : L.rp) + (long long)b * 3 * HW);
    const float* dme = uptr(L.dp + (long long)b * 2 * HW + (side ? HW : 0));
    const float* dot = uptr(L.dp + (long long)b * 2 * HW + (side ? 0 : HW));

    const int base = cw * 126;
    const int c0 = base + 2 * lane;
    const int c1 = c0 + 1;
    const bool in0 = c0 < W, in1 = c1 < W;
    const int cc = min(c0, W - 2) >> 1;          // clamped float2 index
    const float fc0 = (float)c0, fc1 = (float)c1;

    const bool lastW = (cw == L.nCW - 1);
    const bool own0 = in0 && (c0 < base + 126 || lastW);
    const bool own1 = in1 && (c1 < base + 126 || lastW);
    const bool ownS0 = own0 && (c0 <= W - 3);
    const bool ownS1 = own1 && (c1 <= W - 3);

    const int r0 = rs * SH;
    const int r1 = min(r0 + SH, H);
    const int jend = min(r1 + 1, H - 1);   // jend >= r0+15 for all levels

    v2f Pst[3][5], Lst[3][5];
#pragma unroll
    for (int c = 0; c < 3; ++c)
#pragma unroll
        for (int s = 0; s < 5; ++s) { Pst[c][s] = mkv(0.f, 0.f); Lst[c][s] = mkv(0.f, 0.f); }
    float pd0 = 0.f, pd1 = 0.f;
    v2f pxv[3] = {mkv(0.f,0.f), mkv(0.f,0.f), mkv(0.f,0.f)};

    float f_ss = 0.f, f_l1 = 0.f, f_lr = 0.f, f_ds = 0.f;

    // ---- pipeline stage helpers ----
    auto load_dp = [&](int jj, float& o0, float& o1) {
        float2 dpair = ((const float2*)(dme + (unsigned)jj * (unsigned)W))[cc];
        o0 = dpair.x; o1 = dpair.y;
    };

    auto issue_gathers = [&](float di0, float di1, int jj, RowVals& R) {
        const unsigned ro = (unsigned)jj * (unsigned)W;
        R.d0 = di0; R.d1 = di1;
        float xq0 = fmaf(sgn * di0, Wm1f, fc0);
        float xq1 = fmaf(sgn * di1, Wm1f, fc1);
        float xf0 = floorf(xq0), xf1 = floorf(xq1);
        int g0 = (int)xf0, g1 = (int)xf1;
        float t0 = xq0 - xf0, t1 = xq1 - xf1;
        float w00 = (g0 >= 0 && g0 < W)         ? 1.0f - t0 : 0.0f;
        float w01 = (g0 >= -1 && g0 < W - 1)    ? t0        : 0.0f;
        float w10 = (g1 >= 0 && g1 < W)         ? 1.0f - t1 : 0.0f;
        float w11 = (g1 >= -1 && g1 < W - 1)    ? t1        : 0.0f;
        R.wI = mkv(w00, w10);
        R.wJ = mkv(w01, w11);
        unsigned a0 = ro + (unsigned)min(max(g0, 0), W - 1);
        unsigned a1 = ro + (unsigned)min(max(g0 + 1, 0), W - 1);
        unsigned b0 = ro + (unsigned)min(max(g1, 0), W - 1);
        unsigned b1 = ro + (unsigned)min(max(g1 + 1, 0), W - 1);
        R.dI = mkv(dot[a0], dot[b0]);
        R.dJ = mkv(dot[a1], dot[b1]);
#pragma unroll
        for (int c = 0; c < 3; ++c) {
            const unsigned co = (unsigned)c * HWu;
            float2 xp2 = ((const float2*)(xim + co + ro))[cc];
            R.xv[c] = mkv(in0 ? xp2.x : 0.f, in1 ? xp2.y : 0.f);
            R.sI[c] = mkv(sim[co + a0], sim[co + b0]);
            R.sJ[c] = mkv(sim[co + a1], sim[co + b1]);
        }
    };

    auto consume = [&](const RowVals& R, int j) {
        const float d0 = R.d0, d1 = R.d1;
        v2f wv2 = R.dI * R.wI + R.dJ * R.wJ;       // {wv0, wv1}
        v2f xv[3], yv[3];
#pragma unroll
        for (int c = 0; c < 3; ++c) {
            xv[c] = R.xv[c];
            v2f y = R.sI[c] * R.wI + R.sJ[c] * R.wJ;
            yv[c].x = in0 ? y.x : 0.f;
            yv[c].y = in1 ? y.y : 0.f;
        }

        const bool rowOwn = j < r1;
        if (rowOwn) {
            if (own0) {
                f_l1 += fabsf(xv[0].x - yv[0].x) + fabsf(xv[1].x - yv[1].x) + fabsf(xv[2].x - yv[2].x);
                f_lr += fabsf(d0 - wv2.x);
            }
            if (own1) {
                f_l1 += fabsf(xv[0].y - yv[0].y) + fabsf(xv[1].y - yv[1].y) + fabsf(xv[2].y - yv[2].y);
                f_lr += fabsf(d1 - wv2.y);
            }
        }

        // smoothness x-gradients (single-op DPP neighbor pulls)
        {
            float dn  = dpp_shl1(d0);
            float xn0 = dpp_shl1(xv[0].x);
            float xn1 = dpp_shl1(xv[1].x);
            float xn2 = dpp_shl1(xv[2].x);
            if (rowOwn) {
                if (own0 && c0 < W - 1) {
                    float g = fabsf(xv[0].x - xv[0].y) + fabsf(xv[1].x - xv[1].y) + fabsf(xv[2].x - xv[2].y);
                    f_ds += fabsf((d0 - d1) * __expf(-g * (1.0f / 3.0f)));
                }
                if (own1 && c1 < W - 1) {
                    float g = fabsf(xv[0].y - xn0) + fabsf(xv[1].y - xn1) + fabsf(xv[2].y - xn2);
                    f_ds += fabsf((d1 - dn) * __expf(-g * (1.0f / 3.0f)));
                }
            }
        }
        // smoothness y-gradients (prev row in regs)
        if (j > r0 && (j - 1) < r1) {
            v2f t0 = pxv[0] - xv[0];
            v2f t1 = pxv[1] - xv[1];
            v2f t2 = pxv[2] - xv[2];
            if (own0) {
                float g = fabsf(t0.x) + fabsf(t1.x) + fabsf(t2.x);
                f_ds += fabsf((pd0 - d0) * __expf(-g * (1.0f / 3.0f)));
            }
            if (own1) {
                float g = fabsf(t0.y) + fabsf(t1.y) + fabsf(t2.y);
                f_ds += fabsf((pd1 - d1) * __expf(-g * (1.0f / 3.0f)));
            }
        }
        pd0 = d0; pd1 = d1;
#pragma unroll
        for (int c = 0; c < 3; ++c) pxv[c] = xv[c];

        const bool emit = (j >= r0 + 2);  // wave-uniform
#pragma unroll
        for (int c = 0; c < 3; ++c) {
            v2f X = xv[c], Y = yv[c];
            v2f V[5];
            V[0] = X; V[1] = Y;
            V[2] = X * X; V[3] = Y * Y; V[4] = X * Y;
            v2f cs[5];
#pragma unroll
            for (int s = 0; s < 5; ++s) {
                cs[s] = Pst[c][s] + V[s];
                Pst[c][s] = Lst[c][s] + V[s];
                Lst[c][s] = V[s];
            }
            if (emit) {
                v2f Wn[5];
#pragma unroll
                for (int s = 0; s < 5; ++s) {
                    float n0 = dpp_shl1(cs[s].x);
                    float n1 = dpp_shl1(cs[s].y);
                    Wn[s].x = cs[s].x + cs[s].y + n0;
                    Wn[s].y = cs[s].y + n0 + n1;
                }
                v2f ts = ssim_term2(Wn[0], Wn[1], Wn[2], Wn[3], Wn[4]);
                f_ss += (ownS0 ? ts.x : 0.f) + (ownS1 ? ts.y : 0.f);
            }
        }
    };

    // ---- 4-stage pipelined row loop: 3 RowVals buffers (rows j+1..j+3 in
    // flight while consuming row j); dme pre-loads rotate 3 phases ahead.
    // vmcnt retires in issue order, so waiting on buffer X's loads leaves the
    // younger buffers' loads in flight (counted-vmcnt idiom).
    RowVals A, B, C;
    float tA0, tA1, tB0, tB1, tC0, tC1;
    load_dp(r0,     tA0, tA1);
    load_dp(r0 + 1, tB0, tB1);
    load_dp(r0 + 2, tC0, tC1);
    issue_gathers(tA0, tA1, r0,     A);
    issue_gathers(tB0, tB1, r0 + 1, B);
    issue_gathers(tC0, tC1, r0 + 2, C);
    load_dp(min(r0 + 3, jend), tA0, tA1);
    load_dp(min(r0 + 4, jend), tB0, tB1);
    load_dp(min(r0 + 5, jend), tC0, tC1);

    int j = r0;
    for (;;) {
        // phase A
        consume(A, j);
        if (j + 3 <= jend) issue_gathers(tA0, tA1, j + 3, A);
        load_dp(min(j + 6, jend), tA0, tA1);
        if (++j > jend) break;

        // phase B
        consume(B, j);
        if (j + 3 <= jend) issue_gathers(tB0, tB1, j + 3, B);
        load_dp(min(j + 6, jend), tB0, tB1);
        if (++j > jend) break;

        // phase C
        consume(C, j);
        if (j + 3 <= jend) issue_gathers(tC0, tC1, j + 3, C);
        load_dp(min(j + 6, jend), tC0, tC1);
        if (++j > jend) break;
    }

    // ---- reduction ----
#pragma unroll
    for (int o = 32; o > 0; o >>= 1) {
        f_ss += __shfl_down(f_ss, o);
        f_l1 += __shfl_down(f_l1, o);
        f_lr += __shfl_down(f_lr, o);
        f_ds += __shfl_down(f_ds, o);
    }
    __shared__ float red[BDIM / 64][4];
    __shared__ int meta[2];
    if (threadIdx.x == 0) { meta[0] = level; meta[1] = side; }
    if (lane == 0) {
        red[wid][0] = f_ss; red[wid][1] = f_l1;
        red[wid][2] = f_lr; red[wid][3] = f_ds;
    }
    __syncthreads();
    if (threadIdx.x < 4) {
        int t = threadIdx.x;
        double s = (double)red[0][t] + (double)red[1][t]
                 + (double)red[2][t] + (double)red[3][t];
        atomicAdd(acc + t * 8 + meta[1] * 4 + meta[0], s);
    }
}

__global__ void finalize_kernel(const double* __restrict__ acc, float* __restrict__ out) {
    const int B = 32, H0 = 256, W0 = 512;
    double AP = 0.0, LR = 0.0, DS = 0.0;
    for (int i = 0; i < 4; ++i) {
        int h = H0 >> i, w = W0 >> i;
        double nss = (double)B * 3.0 * (double)(h - 2) * (double)(w - 2);
        double nl1 = (double)B * 3.0 * (double)h * (double)w;
        double nd  = (double)B * (double)h * (double)w;
        AP += 0.85 * (acc[0 + i] / nss) + 0.15 * (acc[8 + i] / nl1);
        AP += 0.85 * (acc[4 + i] / nss) + 0.15 * (acc[12 + i] / nl1);
        LR += acc[16 + i] / nd + acc[20 + i] / nd;
        double sc = 1.0 / (double)(1 << i);
        DS += (acc[24 + i] / nd) * sc + (acc[28 + i] / nd) * sc;
    }
    AP *= 0.85;
    DS *= 0.1;
    double total = AP + LR + DS;
    out[0] = (float)total;
    out[1] = (float)AP;
    out[2] = (float)LR;
    out[3] = (float)DS;
}

// ---------------- host launch ----------------
extern "C" void kernel_launch(void* const* d_in, const int* in_sizes, int n_in,
                              void* d_out, int out_size, void* d_ws, size_t ws_size,
                              hipStream_t stream) {
    const int B = 32, H0 = 256, W0 = 512;
    const float* dsp[4];
    for (int i = 0; i < 4; ++i) dsp[i] = (const float*)d_in[i];
    const float* left  = (const float*)d_in[4];
    const float* right = (const float*)d_in[5];
    float* out = (float*)d_out;

    double* acc = (double*)d_ws;
    float* buf = (float*)((char*)d_ws + 256);

    const float* lp[4];
    const float* rp[4];
    float* lpm[4];
    float* rpm[4];
    lp[0] = left; rp[0] = right;
    float* cur = buf;
    for (int i = 1; i < 4; ++i) { lpm[i] = cur; cur += (long long)B * 3 * (H0 >> i) * (W0 >> i); }
    for (int i = 1; i < 4; ++i) { rpm[i] = cur; cur += (long long)B * 3 * (H0 >> i) * (W0 >> i); }
    for (int i = 1; i < 4; ++i) { lp[i] = lpm[i]; rp[i] = rpm[i]; }

    for (int i = 1; i < 4; ++i) {
        int Hs = H0 >> (i - 1), Ws = W0 >> (i - 1);
        int Hd = H0 >> i, Wd = W0 >> i;
        long long half = (long long)B * 3 * Hd * Wd;
        int g = (int)((2 * half + BDIM - 1) / BDIM);
        resize2_kernel<<<g, BDIM, 0, stream>>>(
            lp[i - 1], rp[i - 1], lpm[i], rpm[i], B * 3, Hs, Ws, Hd, Wd,
            acc, (i == 1) ? 1 : 0);
    }

    AllParams P;
    int wb = 0;
    for (int i = 0; i < 4; ++i) {
        int h = H0 >> i, w = W0 >> i;
        LevelDesc& L = P.lv[i];
        L.lp = lp[i]; L.rp = rp[i]; L.dp = dsp[i];
        L.H = h; L.W = w;
        L.nCW = (w - 2 + 125) / 126;
        L.nRS = h / SH;
        L.nPerSide = B * L.nRS * L.nCW;
        L.waveBase = wb;
        wb += 2 * L.nPerSide;
    }
    P.totalWaves = wb;
    int blocks = (wb + (BDIM / 64) - 1) / (BDIM / 64);
    mega_kernel<<<blocks, BDIM, 0, stream>>>(P, acc);

    finalize_kernel<<<1, 1, 0, stream>>>(acc, out);
}

// Round 4
// 329.574 us; speedup vs baseline: 1.0776x; 1.0776x over previous
//
#include <hip/hip_runtime.h>

#define BDIM 256
#define SH 16

typedef float v2f __attribute__((ext_vector_type(2)));

struct LevelDesc {
    const float* lp; const float* rp; const float* dp;
    int H, W, nCW, nRS, nPerSide, waveBase;
};
struct AllParams { LevelDesc lv[4]; int totalWaves; };

// lane i <- lane i+1 (v_mov_b32 dpp wave_shl1; single-use results fuse into
// v_add_f32_dpp). Lane 63 gets 0 (bound_ctrl) -- never consumed by ownership.
__device__ __forceinline__ float dpp_shl1(float x) {
    int r = __builtin_amdgcn_update_dpp(0, __float_as_int(x), 0x130, 0xF, 0xF, true);
    return __int_as_float(r);
}

// force a wave-uniform pointer into SGPRs -> saddr-form loads
__device__ __forceinline__ const float* uptr(const float* p) {
    unsigned long long u = (unsigned long long)p;
    unsigned lo = __builtin_amdgcn_readfirstlane((unsigned)u);
    unsigned hi = __builtin_amdgcn_readfirstlane((unsigned)(u >> 32));
    return (const float*)(((unsigned long long)hi << 32) | (unsigned long long)lo);
}

__device__ __forceinline__ v2f mkv(float a, float b) { v2f r; r.x = a; r.y = b; return r; }

// ---------------- kernels ----------------

// fused L+R align_corners bilinear resize (+ optional acc/counter zeroing)
__global__ void resize2_kernel(const float* __restrict__ sL, const float* __restrict__ sR,
                               float* __restrict__ dL, float* __restrict__ dR,
                               int BC, int Hs, int Ws, int Hd, int Wd,
                               double* acc, int doZero) {
    if (doZero && blockIdx.x == 0) {
        if (threadIdx.x < 32) acc[threadIdx.x] = 0.0;
        else if (threadIdx.x == 32) ((unsigned*)(acc + 32))[0] = 0u;
    }
    long long half = (long long)BC * Hd * Wd;
    long long idx = (long long)blockIdx.x * blockDim.x + threadIdx.x;
    if (idx >= 2 * half) return;
    const float* src = (idx < half) ? sL : sR;
    float* dst = (idx < half) ? dL : dR;
    long long id = (idx < half) ? idx : idx - half;
    int i = (int)(id % Wd);
    long long t = id / Wd;
    int j = (int)(t % Hd);
    int bc = (int)(t / Hd);
    float stepy = (float)(Hs - 1) / (float)(Hd - 1);
    float stepx = (float)(Ws - 1) / (float)(Wd - 1);
    float y = j * stepy;
    float x = i * stepx;
    int y0 = (int)floorf(y);
    int y1 = min(y0 + 1, Hs - 1);
    int x0 = (int)floorf(x);
    int x1 = min(x0 + 1, Ws - 1);
    float wy = y - (float)y0;
    float wx = x - (float)x0;
    const float* s = src + (long long)bc * Hs * Ws;
    float t0 = s[(long long)y0 * Ws + x0] * (1.0f - wy) + s[(long long)y1 * Ws + x0] * wy;
    float t1 = s[(long long)y0 * Ws + x1] * (1.0f - wy) + s[(long long)y1 * Ws + x1] * wy;
    dst[id] = t0 * (1.0f - wx) + t1 * wx;
}

// packed (both px of a lane-pair) SSIM term
__device__ __forceinline__ v2f ssim_term2(v2f Sx, v2f Sy, v2f Sxx, v2f Syy, v2f Sxy) {
    const float C1v = 0.0001f;
    const float C2v = 0.0009f;
    const float i9 = 1.0f / 9.0f;
    v2f mux = Sx * i9, muy = Sy * i9;
    v2f sigx = Sxx * i9 - mux * mux;
    v2f sigy = Syy * i9 - muy * muy;
    v2f cov  = Sxy * i9 - mux * muy;
    v2f num = ((2.0f * mux) * muy + C1v) * (2.0f * cov + C2v);
    v2f den = (mux * mux + muy * muy + C1v) * (sigx + sigy + C2v);
    v2f r;
    r.x = __builtin_amdgcn_rcpf(den.x);
    r.y = __builtin_amdgcn_rcpf(den.y);
    v2f v = (1.0f - num * r) * 0.5f;
    v2f o;
    o.x = __builtin_amdgcn_fmed3f(v.x, 0.0f, 1.0f);
    o.y = __builtin_amdgcn_fmed3f(v.y, 0.0f, 1.0f);
    return o;
}

// Per-row load stage (software pipeline buffer), pair-packed layout.
struct RowVals {
    float d0, d1;
    v2f xv[3];
    v2f wI, wJ;        // {w00,w10}, {w01,w11}  (in0/in1 folded in)
    v2f dI, dJ;        // {dot[a0],dot[b0]}, {dot[a1],dot[b1]}
    v2f sI[3], sJ[3];  // sampled-image gathers per channel
};

__global__ void __launch_bounds__(BDIM)
mega_kernel(AllParams P, double* __restrict__ acc, float* __restrict__ out) {
    const int lane = threadIdx.x & 63;
    const int wid  = threadIdx.x >> 6;
    const int wId  = blockIdx.x * (BDIM / 64) + wid;
    const int w = min(wId, P.totalWaves - 1);

    int level = 0;
    if (w >= P.lv[1].waveBase) level = 1;
    if (w >= P.lv[2].waveBase) level = 2;
    if (w >= P.lv[3].waveBase) level = 3;
    LevelDesc L;
    if (level == 0) L = P.lv[0];
    else if (level == 1) L = P.lv[1];
    else if (level == 2) L = P.lv[2];
    else L = P.lv[3];

    int rel = w - L.waveBase;
    const int side = (rel >= L.nPerSide) ? 1 : 0;
    rel -= side * L.nPerSide;
    const int cw = rel % L.nCW; rel /= L.nCW;
    const int rs = rel % L.nRS;
    const int b  = rel / L.nRS;

    const int H = L.H, W = L.W;
    const long long HW = (long long)H * W;
    const unsigned HWu = (unsigned)HW;
    const float Wm1f = (float)(W - 1);
    const float sgn = side ? 1.0f : -1.0f;

    const float* xim = uptr((side ? L.rp : L.lp) + (long long)b * 3 * HW);
    const float* sim = uptr((side ? L.lp : L.rp) + (long long)b * 3 * HW);
    const float* dme = uptr(L.dp + (long long)b * 2 * HW + (side ? HW : 0));
    const float* dot = uptr(L.dp + (long long)b * 2 * HW + (side ? 0 : HW));

    const int base = cw * 126;
    const int c0 = base + 2 * lane;
    const int c1 = c0 + 1;
    const bool in0 = c0 < W, in1 = c1 < W;
    const int cc = min(c0, W - 2) >> 1;          // clamped float2 index
    const float fc0 = (float)c0, fc1 = (float)c1;

    const bool lastW = (cw == L.nCW - 1);
    const bool own0 = in0 && (c0 < base + 126 || lastW);
    const bool own1 = in1 && (c1 < base + 126 || lastW);
    const bool ownS0 = own0 && (c0 <= W - 3);
    const bool ownS1 = own1 && (c1 <= W - 3);

    // loop-invariant 0/1 mask floats (fma-predication; dead-lane vals finite)
    const float mO0 = own0 ? 1.f : 0.f, mO1 = own1 ? 1.f : 0.f;
    const float mS0 = ownS0 ? 1.f : 0.f, mS1 = ownS1 ? 1.f : 0.f;
    const float mX0 = (own0 && c0 < W - 1) ? 1.f : 0.f;
    const float mX1 = (own1 && c1 < W - 1) ? 1.f : 0.f;

    const int r0 = rs * SH;
    const int r1 = min(r0 + SH, H);
    const int jend = min(r1 + 1, H - 1);

    v2f Pst[3][5], Lst[3][5];
#pragma unroll
    for (int c = 0; c < 3; ++c)
#pragma unroll
        for (int s = 0; s < 5; ++s) { Pst[c][s] = mkv(0.f, 0.f); Lst[c][s] = mkv(0.f, 0.f); }
    float pd0 = 0.f, pd1 = 0.f;
    v2f pxv[3] = {mkv(0.f,0.f), mkv(0.f,0.f), mkv(0.f,0.f)};

    float f_ss = 0.f, f_l1 = 0.f, f_lr = 0.f, f_ds = 0.f;

    // ---- pipeline stage helpers ----
    auto load_dp = [&](int jj, float& o0, float& o1) {
        float2 dpair = ((const float2*)(dme + (unsigned)jj * (unsigned)W))[cc];
        o0 = dpair.x; o1 = dpair.y;
    };

    auto issue_gathers = [&](float di0, float di1, int jj, RowVals& R) {
        const unsigned ro = (unsigned)jj * (unsigned)W;
        R.d0 = di0; R.d1 = di1;
        float xq0 = fmaf(sgn * di0, Wm1f, fc0);
        float xq1 = fmaf(sgn * di1, Wm1f, fc1);
        float xf0 = floorf(xq0), xf1 = floorf(xq1);
        int g0 = (int)xf0, g1 = (int)xf1;
        float t0 = xq0 - xf0, t1 = xq1 - xf1;
        // in0/in1 folded into the weights: out-of-window lanes sample as 0
        float w00 = (in0 && g0 >= 0 && g0 < W)         ? 1.0f - t0 : 0.0f;
        float w01 = (in0 && g0 >= -1 && g0 < W - 1)    ? t0        : 0.0f;
        float w10 = (in1 && g1 >= 0 && g1 < W)         ? 1.0f - t1 : 0.0f;
        float w11 = (in1 && g1 >= -1 && g1 < W - 1)    ? t1        : 0.0f;
        R.wI = mkv(w00, w10);
        R.wJ = mkv(w01, w11);
        unsigned a0 = ro + (unsigned)min(max(g0, 0), W - 1);
        unsigned a1 = ro + (unsigned)min(max(g0 + 1, 0), W - 1);
        unsigned b0 = ro + (unsigned)min(max(g1, 0), W - 1);
        unsigned b1 = ro + (unsigned)min(max(g1 + 1, 0), W - 1);
        R.dI = mkv(dot[a0], dot[b0]);
        R.dJ = mkv(dot[a1], dot[b1]);
#pragma unroll
        for (int c = 0; c < 3; ++c) {
            const unsigned co = (unsigned)c * HWu;
            float2 xp2 = ((const float2*)(xim + co + ro))[cc];
            R.xv[c] = mkv(in0 ? xp2.x : 0.f, in1 ? xp2.y : 0.f);
            R.sI[c] = mkv(sim[co + a0], sim[co + b0]);
            R.sJ[c] = mkv(sim[co + a1], sim[co + b1]);
        }
    };

    auto consume = [&](const RowVals& R, int j) {
        const float d0 = R.d0, d1 = R.d1;
        v2f wv2 = R.dI * R.wI + R.dJ * R.wJ;       // {wv0, wv1}
        v2f xv[3], yv[3];
#pragma unroll
        for (int c = 0; c < 3; ++c) {
            xv[c] = R.xv[c];
            yv[c] = R.sI[c] * R.wI + R.sJ[c] * R.wJ;   // weights carry the mask
        }

        const bool rowOwn = j < r1;                    // wave-uniform
        if (rowOwn) {
            float s0 = fabsf(xv[0].x - yv[0].x) + fabsf(xv[1].x - yv[1].x) + fabsf(xv[2].x - yv[2].x);
            float s1 = fabsf(xv[0].y - yv[0].y) + fabsf(xv[1].y - yv[1].y) + fabsf(xv[2].y - yv[2].y);
            f_l1 = fmaf(mO0, s0, f_l1);
            f_l1 = fmaf(mO1, s1, f_l1);
            f_lr = fmaf(mO0, fabsf(d0 - wv2.x), f_lr);
            f_lr = fmaf(mO1, fabsf(d1 - wv2.y), f_lr);
        }

        // smoothness x-gradients (DPP neighbor pulls, single-use -> fused)
        {
            float dn  = dpp_shl1(d0);
            float xn0 = dpp_shl1(xv[0].x);
            float xn1 = dpp_shl1(xv[1].x);
            float xn2 = dpp_shl1(xv[2].x);
            if (rowOwn) {
                float g0v = fabsf(xv[0].x - xv[0].y) + fabsf(xv[1].x - xv[1].y) + fabsf(xv[2].x - xv[2].y);
                float g1v = fabsf(xv[0].y - xn0) + fabsf(xv[1].y - xn1) + fabsf(xv[2].y - xn2);
                f_ds = fmaf(mX0, fabsf((d0 - d1) * __expf(-g0v * (1.0f / 3.0f))), f_ds);
                f_ds = fmaf(mX1, fabsf((d1 - dn) * __expf(-g1v * (1.0f / 3.0f))), f_ds);
            }
        }
        // smoothness y-gradients (prev row in regs)
        if (j > r0 && (j - 1) < r1) {                  // wave-uniform
            v2f t0 = pxv[0] - xv[0];
            v2f t1 = pxv[1] - xv[1];
            v2f t2 = pxv[2] - xv[2];
            float g0v = fabsf(t0.x) + fabsf(t1.x) + fabsf(t2.x);
            float g1v = fabsf(t0.y) + fabsf(t1.y) + fabsf(t2.y);
            f_ds = fmaf(mO0, fabsf((pd0 - d0) * __expf(-g0v * (1.0f / 3.0f))), f_ds);
            f_ds = fmaf(mO1, fabsf((pd1 - d1) * __expf(-g1v * (1.0f / 3.0f))), f_ds);
        }
        pd0 = d0; pd1 = d1;
#pragma unroll
        for (int c = 0; c < 3; ++c) pxv[c] = xv[c];

        const bool emit = (j >= r0 + 2);  // wave-uniform
#pragma unroll
        for (int c = 0; c < 3; ++c) {
            v2f X = xv[c], Y = yv[c];
            v2f V[5];
            V[0] = X; V[1] = Y;
            V[2] = X * X; V[3] = Y * Y; V[4] = X * Y;
            v2f cs[5];
#pragma unroll
            for (int s = 0; s < 5; ++s) {
                cs[s] = Pst[c][s] + V[s];
                Pst[c][s] = Lst[c][s] + V[s];
                Lst[c][s] = V[s];
            }
            if (emit) {
                v2f Wn[5];
#pragma unroll
                for (int s = 0; s < 5; ++s) {
                    // n0+n1 == shl1(cs.x+cs.y): 3 instr instead of 6
                    float s0 = cs[s].x + cs[s].y;
                    Wn[s].x = s0 + dpp_shl1(cs[s].x);
                    Wn[s].y = cs[s].y + dpp_shl1(s0);
                }
                v2f ts = ssim_term2(Wn[0], Wn[1], Wn[2], Wn[3], Wn[4]);
                f_ss = fmaf(mS0, ts.x, f_ss);
                f_ss = fmaf(mS1, ts.y, f_ss);
            }
        }
    };

    // ---- 3-stage pipelined row loop (R2-proven: 2 buffers, 92 VGPR) ----
    RowVals A, B;
    float dq0, dq1, dn0, dn1;
    load_dp(r0, dq0, dq1);
    load_dp(min(r0 + 1, jend), dn0, dn1);
    issue_gathers(dq0, dq1, r0, A);

    int j = r0;
    for (;;) {
        float dp20, dp21;
        load_dp(min(j + 2, jend), dp20, dp21);
        if (j < jend) issue_gathers(dn0, dn1, j + 1, B);
        consume(A, j);
        dn0 = dp20; dn1 = dp21;
        if (++j > jend) break;

        load_dp(min(j + 2, jend), dp20, dp21);
        if (j < jend) issue_gathers(dn0, dn1, j + 1, A);
        consume(B, j);
        dn0 = dp20; dn1 = dp21;
        if (++j > jend) break;
    }

    // ---- reduction ----
#pragma unroll
    for (int o = 32; o > 0; o >>= 1) {
        f_ss += __shfl_down(f_ss, o);
        f_l1 += __shfl_down(f_l1, o);
        f_lr += __shfl_down(f_lr, o);
        f_ds += __shfl_down(f_ds, o);
    }
    __shared__ float red[BDIM / 64][4];
    __shared__ int meta[2];
    if (threadIdx.x == 0) { meta[0] = level; meta[1] = side; }
    if (lane == 0) {
        red[wid][0] = f_ss; red[wid][1] = f_l1;
        red[wid][2] = f_lr; red[wid][3] = f_ds;
    }
    __syncthreads();
    if (threadIdx.x < 4) {
        int t = threadIdx.x;
        double s = (double)red[0][t] + (double)red[1][t]
                 + (double)red[2][t] + (double)red[3][t];
        atomicAdd(acc + t * 8 + meta[1] * 4 + meta[0], s);
    }
    __syncthreads();

    // ---- last-block finalize (removes a separate launch) ----
    if (threadIdx.x == 0) {
        __threadfence();
        unsigned old = atomicAdd((unsigned*)(acc + 32), 1u);
        if (old == (unsigned)(gridDim.x - 1)) {
            __threadfence();
            const int B_ = 32, H0 = 256, W0 = 512;
            double AP = 0.0, LR = 0.0, DS = 0.0;
            for (int i = 0; i < 4; ++i) {
                int h = H0 >> i, ww = W0 >> i;
                double nss = (double)B_ * 3.0 * (double)(h - 2) * (double)(ww - 2);
                double nl1 = (double)B_ * 3.0 * (double)h * (double)ww;
                double nd  = (double)B_ * (double)h * (double)ww;
                // coherent readback via atomic RMW (cross-XCD safe)
                double a0  = atomicAdd(acc + 0  + i, 0.0);
                double a4  = atomicAdd(acc + 4  + i, 0.0);
                double a8  = atomicAdd(acc + 8  + i, 0.0);
                double a12 = atomicAdd(acc + 12 + i, 0.0);
                double a16 = atomicAdd(acc + 16 + i, 0.0);
                double a20 = atomicAdd(acc + 20 + i, 0.0);
                double a24 = atomicAdd(acc + 24 + i, 0.0);
                double a28 = atomicAdd(acc + 28 + i, 0.0);
                AP += 0.85 * (a0 / nss) + 0.15 * (a8 / nl1);
                AP += 0.85 * (a4 / nss) + 0.15 * (a12 / nl1);
                LR += a16 / nd + a20 / nd;
                double sc = 1.0 / (double)(1 << i);
                DS += (a24 / nd) * sc + (a28 / nd) * sc;
            }
            AP *= 0.85;
            DS *= 0.1;
            double total = AP + LR + DS;
            out[0] = (float)total;
            out[1] = (float)AP;
            out[2] = (float)LR;
            out[3] = (float)DS;
        }
    }
}

// ---------------- host launch ----------------
extern "C" void kernel_launch(void* const* d_in, const int* in_sizes, int n_in,
                              void* d_out, int out_size, void* d_ws, size_t ws_size,
                              hipStream_t stream) {
    const int B = 32, H0 = 256, W0 = 512;
    const float* dsp[4];
    for (int i = 0; i < 4; ++i) dsp[i] = (const float*)d_in[i];
    const float* left  = (const float*)d_in[4];
    const float* right = (const float*)d_in[5];
    float* out = (float*)d_out;

    double* acc = (double*)d_ws;                 // 32 doubles + counter
    float* buf = (float*)((char*)d_ws + 512);

    const float* lp[4];
    const float* rp[4];
    float* lpm[4];
    float* rpm[4];
    lp[0] = left; rp[0] = right;
    float* cur = buf;
    for (int i = 1; i < 4; ++i) { lpm[i] = cur; cur += (long long)B * 3 * (H0 >> i) * (W0 >> i); }
    for (int i = 1; i < 4; ++i) { rpm[i] = cur; cur += (long long)B * 3 * (H0 >> i) * (W0 >> i); }
    for (int i = 1; i < 4; ++i) { lp[i] = lpm[i]; rp[i] = rpm[i]; }

    for (int i = 1; i < 4; ++i) {
        int Hs = H0 >> (i - 1), Ws = W0 >> (i - 1);
        int Hd = H0 >> i, Wd = W0 >> i;
        long long half = (long long)B * 3 * Hd * Wd;
        int g = (int)((2 * half + BDIM - 1) / BDIM);
        resize2_kernel<<<g, BDIM, 0, stream>>>(
            lp[i - 1], rp[i - 1], lpm[i], rpm[i], B * 3, Hs, Ws, Hd, Wd,
            acc, (i == 1) ? 1 : 0);
    }

    AllParams P;
    int wb = 0;
    for (int i = 0; i < 4; ++i) {
        int h = H0 >> i, w = W0 >> i;
        LevelDesc& L = P.lv[i];
        L.lp = lp[i]; L.rp = rp[i]; L.dp = dsp[i];
        L.H = h; L.W = w;
        L.nCW = (w - 2 + 125) / 126;
        L.nRS = h / SH;
        L.nPerSide = B * L.nRS * L.nCW;
        L.waveBase = wb;
        wb += 2 * L.nPerSide;
    }
    P.totalWaves = wb;
    int blocks = (wb + (BDIM / 64) - 1) / (BDIM / 64);
    mega_kernel<<<blocks, BDIM, 0, stream>>>(P, acc, out);
}

// Round 5
// 282.372 us; speedup vs baseline: 1.2577x; 1.1672x over previous
//
#include <hip/hip_runtime.h>

#define BDIM 256
#define SH 16

typedef float v2f __attribute__((ext_vector_type(2)));

struct LevelDesc {
    const float* lp; const float* rp; const float* dp;
    int H, W, nCW, nRS, nPerSide, waveBase;
};
struct AllParams { LevelDesc lv[4]; int totalWaves; };

// lane i <- lane i+1 (v_mov_b32 dpp wave_shl1; single-use results fuse into
// v_add_f32_dpp). Lane 63 gets 0 (bound_ctrl) -- never consumed by ownership.
__device__ __forceinline__ float dpp_shl1(float x) {
    int r = __builtin_amdgcn_update_dpp(0, __float_as_int(x), 0x130, 0xF, 0xF, true);
    return __int_as_float(r);
}

// force a wave-uniform pointer into SGPRs -> saddr-form loads
__device__ __forceinline__ const float* uptr(const float* p) {
    unsigned long long u = (unsigned long long)p;
    unsigned lo = __builtin_amdgcn_readfirstlane((unsigned)u);
    unsigned hi = __builtin_amdgcn_readfirstlane((unsigned)(u >> 32));
    return (const float*)(((unsigned long long)hi << 32) | (unsigned long long)lo);
}

__device__ __forceinline__ v2f mkv(float a, float b) { v2f r; r.x = a; r.y = b; return r; }

// ---------------- kernels ----------------

// fused L+R align_corners bilinear resize (+ optional acc zeroing)
__global__ void resize2_kernel(const float* __restrict__ sL, const float* __restrict__ sR,
                               float* __restrict__ dL, float* __restrict__ dR,
                               int BC, int Hs, int Ws, int Hd, int Wd,
                               double* acc, int doZero) {
    if (doZero && blockIdx.x == 0 && threadIdx.x < 32) acc[threadIdx.x] = 0.0;
    long long half = (long long)BC * Hd * Wd;
    long long idx = (long long)blockIdx.x * blockDim.x + threadIdx.x;
    if (idx >= 2 * half) return;
    const float* src = (idx < half) ? sL : sR;
    float* dst = (idx < half) ? dL : dR;
    long long id = (idx < half) ? idx : idx - half;
    int i = (int)(id % Wd);
    long long t = id / Wd;
    int j = (int)(t % Hd);
    int bc = (int)(t / Hd);
    float stepy = (float)(Hs - 1) / (float)(Hd - 1);
    float stepx = (float)(Ws - 1) / (float)(Wd - 1);
    float y = j * stepy;
    float x = i * stepx;
    int y0 = (int)floorf(y);
    int y1 = min(y0 + 1, Hs - 1);
    int x0 = (int)floorf(x);
    int x1 = min(x0 + 1, Ws - 1);
    float wy = y - (float)y0;
    float wx = x - (float)x0;
    const float* s = src + (long long)bc * Hs * Ws;
    float t0 = s[(long long)y0 * Ws + x0] * (1.0f - wy) + s[(long long)y1 * Ws + x0] * wy;
    float t1 = s[(long long)y0 * Ws + x1] * (1.0f - wy) + s[(long long)y1 * Ws + x1] * wy;
    dst[id] = t0 * (1.0f - wx) + t1 * wx;
}

// packed (both px of a lane-pair) SSIM term
__device__ __forceinline__ v2f ssim_term2(v2f Sx, v2f Sy, v2f Sxx, v2f Syy, v2f Sxy) {
    const float C1v = 0.0001f;
    const float C2v = 0.0009f;
    const float i9 = 1.0f / 9.0f;
    v2f mux = Sx * i9, muy = Sy * i9;
    v2f sigx = Sxx * i9 - mux * mux;
    v2f sigy = Syy * i9 - muy * muy;
    v2f cov  = Sxy * i9 - mux * muy;
    v2f num = ((2.0f * mux) * muy + C1v) * (2.0f * cov + C2v);
    v2f den = (mux * mux + muy * muy + C1v) * (sigx + sigy + C2v);
    v2f r;
    r.x = __builtin_amdgcn_rcpf(den.x);
    r.y = __builtin_amdgcn_rcpf(den.y);
    v2f v = (1.0f - num * r) * 0.5f;
    v2f o;
    o.x = __builtin_amdgcn_fmed3f(v.x, 0.0f, 1.0f);
    o.y = __builtin_amdgcn_fmed3f(v.y, 0.0f, 1.0f);
    return o;
}

// Per-row load stage (software pipeline buffer), pair-packed layout.
struct RowVals {
    float d0, d1;
    v2f xv[3];
    v2f wI, wJ;        // {w00,w10}, {w01,w11}  (in0/in1 folded in)
    v2f dI, dJ;        // {dot[a0],dot[b0]}, {dot[a1],dot[b1]}
    v2f sI[3], sJ[3];  // sampled-image gathers per channel
};

__global__ void __launch_bounds__(BDIM)
mega_kernel(AllParams P, double* __restrict__ acc) {
    const int lane = threadIdx.x & 63;
    const int wid  = threadIdx.x >> 6;
    const int wId  = blockIdx.x * (BDIM / 64) + wid;
    const int w = min(wId, P.totalWaves - 1);

    int level = 0;
    if (w >= P.lv[1].waveBase) level = 1;
    if (w >= P.lv[2].waveBase) level = 2;
    if (w >= P.lv[3].waveBase) level = 3;
    LevelDesc L;
    if (level == 0) L = P.lv[0];
    else if (level == 1) L = P.lv[1];
    else if (level == 2) L = P.lv[2];
    else L = P.lv[3];

    int rel = w - L.waveBase;
    const int side = (rel >= L.nPerSide) ? 1 : 0;
    rel -= side * L.nPerSide;
    const int cw = rel % L.nCW; rel /= L.nCW;
    const int rs = rel % L.nRS;
    const int b  = rel / L.nRS;

    const int H = L.H, W = L.W;
    const long long HW = (long long)H * W;
    const unsigned HWu = (unsigned)HW;
    const float Wm1f = (float)(W - 1);
    const float sgn = side ? 1.0f : -1.0f;

    const float* xim = uptr((side ? L.rp : L.lp) + (long long)b * 3 * HW);
    const float* sim = uptr((side ? L.lp : L.rp) + (long long)b * 3 * HW);
    const float* dme = uptr(L.dp + (long long)b * 2 * HW + (side ? HW : 0));
    const float* dot = uptr(L.dp + (long long)b * 2 * HW + (side ? 0 : HW));

    const int base = cw * 126;
    const int c0 = base + 2 * lane;
    const int c1 = c0 + 1;
    const bool in0 = c0 < W, in1 = c1 < W;
    const int cc = min(c0, W - 2) >> 1;          // clamped float2 index
    const float fc0 = (float)c0, fc1 = (float)c1;

    const bool lastW = (cw == L.nCW - 1);
    const bool own0 = in0 && (c0 < base + 126 || lastW);
    const bool own1 = in1 && (c1 < base + 126 || lastW);
    const bool ownS0 = own0 && (c0 <= W - 3);
    const bool ownS1 = own1 && (c1 <= W - 3);

    // loop-invariant 0/1 mask floats (fma-predication; dead-lane vals finite)
    const float mO0 = own0 ? 1.f : 0.f, mO1 = own1 ? 1.f : 0.f;
    const float mS0 = ownS0 ? 1.f : 0.f, mS1 = ownS1 ? 1.f : 0.f;
    const float mX0 = (own0 && c0 < W - 1) ? 1.f : 0.f;
    const float mX1 = (own1 && c1 < W - 1) ? 1.f : 0.f;

    const int r0 = rs * SH;
    const int r1 = min(r0 + SH, H);
    const int jend = min(r1 + 1, H - 1);

    v2f Pst[3][5], Lst[3][5];
#pragma unroll
    for (int c = 0; c < 3; ++c)
#pragma unroll
        for (int s = 0; s < 5; ++s) { Pst[c][s] = mkv(0.f, 0.f); Lst[c][s] = mkv(0.f, 0.f); }
    float pd0 = 0.f, pd1 = 0.f;
    v2f pxv[3] = {mkv(0.f,0.f), mkv(0.f,0.f), mkv(0.f,0.f)};

    float f_ss = 0.f, f_l1 = 0.f, f_lr = 0.f, f_ds = 0.f;

    // ---- pipeline stage helpers ----
    auto load_dp = [&](int jj, float& o0, float& o1) {
        float2 dpair = ((const float2*)(dme + (unsigned)jj * (unsigned)W))[cc];
        o0 = dpair.x; o1 = dpair.y;
    };

    auto issue_gathers = [&](float di0, float di1, int jj, RowVals& R) {
        const unsigned ro = (unsigned)jj * (unsigned)W;
        R.d0 = di0; R.d1 = di1;
        float xq0 = fmaf(sgn * di0, Wm1f, fc0);
        float xq1 = fmaf(sgn * di1, Wm1f, fc1);
        float xf0 = floorf(xq0), xf1 = floorf(xq1);
        int g0 = (int)xf0, g1 = (int)xf1;
        float t0 = xq0 - xf0, t1 = xq1 - xf1;
        // in0/in1 folded into the weights: out-of-window lanes sample as 0
        float w00 = (in0 && g0 >= 0 && g0 < W)         ? 1.0f - t0 : 0.0f;
        float w01 = (in0 && g0 >= -1 && g0 < W - 1)    ? t0        : 0.0f;
        float w10 = (in1 && g1 >= 0 && g1 < W)         ? 1.0f - t1 : 0.0f;
        float w11 = (in1 && g1 >= -1 && g1 < W - 1)    ? t1        : 0.0f;
        R.wI = mkv(w00, w10);
        R.wJ = mkv(w01, w11);
        unsigned a0 = ro + (unsigned)min(max(g0, 0), W - 1);
        unsigned a1 = ro + (unsigned)min(max(g0 + 1, 0), W - 1);
        unsigned b0 = ro + (unsigned)min(max(g1, 0), W - 1);
        unsigned b1 = ro + (unsigned)min(max(g1 + 1, 0), W - 1);
        R.dI = mkv(dot[a0], dot[b0]);
        R.dJ = mkv(dot[a1], dot[b1]);
#pragma unroll
        for (int c = 0; c < 3; ++c) {
            const unsigned co = (unsigned)c * HWu;
            float2 xp2 = ((const float2*)(xim + co + ro))[cc];
            R.xv[c] = mkv(in0 ? xp2.x : 0.f, in1 ? xp2.y : 0.f);
            R.sI[c] = mkv(sim[co + a0], sim[co + b0]);
            R.sJ[c] = mkv(sim[co + a1], sim[co + b1]);
        }
    };

    auto consume = [&](const RowVals& R, int j) {
        const float d0 = R.d0, d1 = R.d1;
        v2f wv2 = R.dI * R.wI + R.dJ * R.wJ;       // {wv0, wv1}
        v2f xv[3], yv[3];
#pragma unroll
        for (int c = 0; c < 3; ++c) {
            xv[c] = R.xv[c];
            yv[c] = R.sI[c] * R.wI + R.sJ[c] * R.wJ;   // weights carry the mask
        }

        const bool rowOwn = j < r1;                    // wave-uniform
        if (rowOwn) {
            float s0 = fabsf(xv[0].x - yv[0].x) + fabsf(xv[1].x - yv[1].x) + fabsf(xv[2].x - yv[2].x);
            float s1 = fabsf(xv[0].y - yv[0].y) + fabsf(xv[1].y - yv[1].y) + fabsf(xv[2].y - yv[2].y);
            f_l1 = fmaf(mO0, s0, f_l1);
            f_l1 = fmaf(mO1, s1, f_l1);
            f_lr = fmaf(mO0, fabsf(d0 - wv2.x), f_lr);
            f_lr = fmaf(mO1, fabsf(d1 - wv2.y), f_lr);
        }

        // smoothness x-gradients (DPP neighbor pulls, single-use -> fused)
        {
            float dn  = dpp_shl1(d0);
            float xn0 = dpp_shl1(xv[0].x);
            float xn1 = dpp_shl1(xv[1].x);
            float xn2 = dpp_shl1(xv[2].x);
            if (rowOwn) {
                float g0v = fabsf(xv[0].x - xv[0].y) + fabsf(xv[1].x - xv[1].y) + fabsf(xv[2].x - xv[2].y);
                float g1v = fabsf(xv[0].y - xn0) + fabsf(xv[1].y - xn1) + fabsf(xv[2].y - xn2);
                f_ds = fmaf(mX0, fabsf((d0 - d1) * __expf(-g0v * (1.0f / 3.0f))), f_ds);
                f_ds = fmaf(mX1, fabsf((d1 - dn) * __expf(-g1v * (1.0f / 3.0f))), f_ds);
            }
        }
        // smoothness y-gradients (prev row in regs)
        if (j > r0 && (j - 1) < r1) {                  // wave-uniform
            v2f t0 = pxv[0] - xv[0];
            v2f t1 = pxv[1] - xv[1];
            v2f t2 = pxv[2] - xv[2];
            float g0v = fabsf(t0.x) + fabsf(t1.x) + fabsf(t2.x);
            float g1v = fabsf(t0.y) + fabsf(t1.y) + fabsf(t2.y);
            f_ds = fmaf(mO0, fabsf((pd0 - d0) * __expf(-g0v * (1.0f / 3.0f))), f_ds);
            f_ds = fmaf(mO1, fabsf((pd1 - d1) * __expf(-g1v * (1.0f / 3.0f))), f_ds);
        }
        pd0 = d0; pd1 = d1;
#pragma unroll
        for (int c = 0; c < 3; ++c) pxv[c] = xv[c];

        const bool emit = (j >= r0 + 2);  // wave-uniform
#pragma unroll
        for (int c = 0; c < 3; ++c) {
            v2f X = xv[c], Y = yv[c];
            v2f V[5];
            V[0] = X; V[1] = Y;
            V[2] = X * X; V[3] = Y * Y; V[4] = X * Y;
            v2f cs[5];
#pragma unroll
            for (int s = 0; s < 5; ++s) {
                cs[s] = Pst[c][s] + V[s];
                Pst[c][s] = Lst[c][s] + V[s];
                Lst[c][s] = V[s];
            }
            if (emit) {
                v2f Wn[5];
#pragma unroll
                for (int s = 0; s < 5; ++s) {
                    // n0+n1 == shl1(cs.x+cs.y): 3 instr instead of 6
                    float s0 = cs[s].x + cs[s].y;
                    Wn[s].x = s0 + dpp_shl1(cs[s].x);
                    Wn[s].y = cs[s].y + dpp_shl1(s0);
                }
                v2f ts = ssim_term2(Wn[0], Wn[1], Wn[2], Wn[3], Wn[4]);
                f_ss = fmaf(mS0, ts.x, f_ss);
                f_ss = fmaf(mS1, ts.y, f_ss);
            }
        }
    };

    // ---- 3-stage pipelined row loop (R2-proven: 2 buffers) ----
    RowVals A, B;
    float dq0, dq1, dn0, dn1;
    load_dp(r0, dq0, dq1);
    load_dp(min(r0 + 1, jend), dn0, dn1);
    issue_gathers(dq0, dq1, r0, A);

    int j = r0;
    for (;;) {
        float dp20, dp21;
        load_dp(min(j + 2, jend), dp20, dp21);
        if (j < jend) issue_gathers(dn0, dn1, j + 1, B);
        consume(A, j);
        dn0 = dp20; dn1 = dp21;
        if (++j > jend) break;

        load_dp(min(j + 2, jend), dp20, dp21);
        if (j < jend) issue_gathers(dn0, dn1, j + 1, A);
        consume(B, j);
        dn0 = dp20; dn1 = dp21;
        if (++j > jend) break;
    }

    // ---- reduction ----
#pragma unroll
    for (int o = 32; o > 0; o >>= 1) {
        f_ss += __shfl_down(f_ss, o);
        f_l1 += __shfl_down(f_l1, o);
        f_lr += __shfl_down(f_lr, o);
        f_ds += __shfl_down(f_ds, o);
    }
    __shared__ float red[BDIM / 64][4];
    __shared__ int meta[2];
    if (threadIdx.x == 0) { meta[0] = level; meta[1] = side; }
    if (lane == 0) {
        red[wid][0] = f_ss; red[wid][1] = f_l1;
        red[wid][2] = f_lr; red[wid][3] = f_ds;
    }
    __syncthreads();
    if (threadIdx.x < 4) {
        int t = threadIdx.x;
        double s = (double)red[0][t] + (double)red[1][t]
                 + (double)red[2][t] + (double)red[3][t];
        atomicAdd(acc + t * 8 + meta[1] * 4 + meta[0], s);
    }
}

__global__ void finalize_kernel(const double* __restrict__ acc, float* __restrict__ out) {
    const int B = 32, H0 = 256, W0 = 512;
    double AP = 0.0, LR = 0.0, DS = 0.0;
    for (int i = 0; i < 4; ++i) {
        int h = H0 >> i, w = W0 >> i;
        double nss = (double)B * 3.0 * (double)(h - 2) * (double)(w - 2);
        double nl1 = (double)B * 3.0 * (double)h * (double)w;
        double nd  = (double)B * (double)h * (double)w;
        AP += 0.85 * (acc[0 + i] / nss) + 0.15 * (acc[8 + i] / nl1);
        AP += 0.85 * (acc[4 + i] / nss) + 0.15 * (acc[12 + i] / nl1);
        LR += acc[16 + i] / nd + acc[20 + i] / nd;
        double sc = 1.0 / (double)(1 << i);
        DS += (acc[24 + i] / nd) * sc + (acc[28 + i] / nd) * sc;
    }
    AP *= 0.85;
    DS *= 0.1;
    double total = AP + LR + DS;
    out[0] = (float)total;
    out[1] = (float)AP;
    out[2] = (float)LR;
    out[3] = (float)DS;
}

// ---------------- host launch ----------------
extern "C" void kernel_launch(void* const* d_in, const int* in_sizes, int n_in,
                              void* d_out, int out_size, void* d_ws, size_t ws_size,
                              hipStream_t stream) {
    const int B = 32, H0 = 256, W0 = 512;
    const float* dsp[4];
    for (int i = 0; i < 4; ++i) dsp[i] = (const float*)d_in[i];
    const float* left  = (const float*)d_in[4];
    const float* right = (const float*)d_in[5];
    float* out = (float*)d_out;

    double* acc = (double*)d_ws;
    float* buf = (float*)((char*)d_ws + 256);

    const float* lp[4];
    const float* rp[4];
    float* lpm[4];
    float* rpm[4];
    lp[0] = left; rp[0] = right;
    float* cur = buf;
    for (int i = 1; i < 4; ++i) { lpm[i] = cur; cur += (long long)B * 3 * (H0 >> i) * (W0 >> i); }
    for (int i = 1; i < 4; ++i) { rpm[i] = cur; cur += (long long)B * 3 * (H0 >> i) * (W0 >> i); }
    for (int i = 1; i < 4; ++i) { lp[i] = lpm[i]; rp[i] = rpm[i]; }

    for (int i = 1; i < 4; ++i) {
        int Hs = H0 >> (i - 1), Ws = W0 >> (i - 1);
        int Hd = H0 >> i, Wd = W0 >> i;
        long long half = (long long)B * 3 * Hd * Wd;
        int g = (int)((2 * half + BDIM - 1) / BDIM);
        resize2_kernel<<<g, BDIM, 0, stream>>>(
            lp[i - 1], rp[i - 1], lpm[i], rpm[i], B * 3, Hs, Ws, Hd, Wd,
            acc, (i == 1) ? 1 : 0);
    }

    AllParams P;
    int wb = 0;
    for (int i = 0; i < 4; ++i) {
        int h = H0 >> i, w = W0 >> i;
        LevelDesc& L = P.lv[i];
        L.lp = lp[i]; L.rp = rp[i]; L.dp = dsp[i];
        L.H = h; L.W = w;
        L.nCW = (w - 2 + 125) / 126;
        L.nRS = h / SH;
        L.nPerSide = B * L.nRS * L.nCW;
        L.waveBase = wb;
        wb += 2 * L.nPerSide;
    }
    P.totalWaves = wb;
    int blocks = (wb + (BDIM / 64) - 1) / (BDIM / 64);
    mega_kernel<<<blocks, BDIM, 0, stream>>>(P, acc);

    finalize_kernel<<<1, 1, 0, stream>>>(acc, out);
}